// Round 3
// baseline (35207.703 us; speedup 1.0000x reference)
//
#include <hip/hip_runtime.h>

// ---------------------------------------------------------------------------
// TransitionDown: FPS (M=N/4) -> KNN(K=16) -> Linear(64->128)+ReLU -> max-pool
// Round 7: the allocator was obeying all along — budget = 256-arch-file /
// min_waves_per_eu. Evidence: (2,2)->128, (4,4)->64, num_vgpr(256) [a max,
// not a floor] -> default 128. VALUBusy=0.25% (64% of the 1-CU ceiling
// 0.39%) with ~2x the useful VALU instr count and FETCH~1MB => the 192-float
// state spills via v_accvgpr reg-reg copies (VALU), not memory.
// Fix: amdgpu_waves_per_eu(1) => budget 256 VGPRs. min=1 only — max
// unspecified so 2 waves/SIMD stay resident (2x256 = 512 unified pool);
// (1,1) would deadlock the 8-wave barrier'd block.
// Structure unchanged from r6: 512 thr x 64 pts (192 floats state),
// z in LDS (128 KiB), u64-key argmax + triple-buffered LDS atomicMax,
// 1 barrier/step, sched_barrier(0) between quarters to cap z-load hoisting.
// ---------------------------------------------------------------------------

#define FPS_T   512
#define KNN_K   16
#define MLP_ROWS 32

typedef float vf16 __attribute__((ext_vector_type(16)));

// --- SoA transpose of pos for coalesced per-coordinate access ---------------
__global__ void prep_kernel(const float* __restrict__ pos, float* __restrict__ posx,
                            float* __restrict__ posy, float* __restrict__ posz, int N)
{
    const int i = blockIdx.x * blockDim.x + threadIdx.x;
    if (i < N) {
        posx[i] = pos[3 * i + 0];
        posy[i] = pos[3 * i + 1];
        posz[i] = pos[3 * i + 2];
    }
}

// --- h = relu(x @ W + b), x[N,64], W[64,128], h[N,128] ----------------------
__global__ __launch_bounds__(256) void mlp_kernel(
    const float* __restrict__ x, const float* __restrict__ W,
    const float* __restrict__ b, float* __restrict__ h, int N)
{
    __shared__ float ws[64 * 128];
    __shared__ float xs[MLP_ROWS * 65];   // +1 pad: breaks 8-way bank conflict
    const int t = threadIdx.x;
    const int r0 = blockIdx.x * MLP_ROWS;

    for (int i = t; i < 64 * 128; i += 256) ws[i] = W[i];
    for (int i = t; i < MLP_ROWS * 64; i += 256) {
        const int r = i >> 6, k = i & 63;
        xs[r * 65 + k] = x[r0 * 64 + i];
    }
    __syncthreads();

    const int tx = t & 31, ty = t >> 5;
    const int c0 = tx * 4, rr = ty * 4;    // 4 rows x 4 cols per thread
    float acc[4][4];
#pragma unroll
    for (int i = 0; i < 4; ++i)
#pragma unroll
        for (int j = 0; j < 4; ++j) acc[i][j] = 0.0f;

    for (int k = 0; k < 64; ++k) {
        const float4 w4 = *(const float4*)(&ws[k * 128 + c0]);
#pragma unroll
        for (int i = 0; i < 4; ++i) {
            const float xv = xs[(rr + i) * 65 + k];
            acc[i][0] += xv * w4.x;
            acc[i][1] += xv * w4.y;
            acc[i][2] += xv * w4.z;
            acc[i][3] += xv * w4.w;
        }
    }
    const float4 b4 = *(const float4*)(&b[c0]);
#pragma unroll
    for (int i = 0; i < 4; ++i) {
        float4 o;
        o.x = fmaxf(acc[i][0] + b4.x, 0.0f);
        o.y = fmaxf(acc[i][1] + b4.y, 0.0f);
        o.z = fmaxf(acc[i][2] + b4.z, 0.0f);
        o.w = fmaxf(acc[i][3] + b4.w, 0.0f);
        *(float4*)(&h[(size_t)(r0 + rr + i) * 128 + c0]) = o;
    }
}

// --- Farthest point sampling: exact sequential semantics --------------------
// idx = [0, pick_0, ..., pick_{M-2}]; pick = argmax of updated mind,
// ties -> lowest index (matches jnp.argmax).
// Ownership: thread t, slot k in [0,64): i = (k>>2)*2048 + 4t + (k&3).
// Ascending i per thread => strict '>' keeps lowest index on tie within a
// thread; the packed u64 key handles cross-thread/cross-wave tie-break.
#define FPS_INIT(PX, PY, MD, VBASE)                                       \
    _Pragma("unroll")                                                     \
    for (int jj = 0; jj < 4; ++jj) {                                      \
        const int j = (VBASE >> 2) + jj;                                  \
        const float4 x4 = *(const float4*)&posx[j * 2048 + (t << 2)];     \
        const float4 y4 = *(const float4*)&posy[j * 2048 + (t << 2)];     \
        PX[jj * 4 + 0] = x4.x; PX[jj * 4 + 1] = x4.y;                     \
        PX[jj * 4 + 2] = x4.z; PX[jj * 4 + 3] = x4.w;                     \
        PY[jj * 4 + 0] = y4.x; PY[jj * 4 + 1] = y4.y;                     \
        PY[jj * 4 + 2] = y4.z; PY[jj * 4 + 3] = y4.w;                     \
        _Pragma("unroll")                                                 \
        for (int c = 0; c < 4; ++c) MD[jj * 4 + c] = __builtin_inff();    \
    }

#define FPS_STEP(PX, PY, MD, VBASE)                                      \
    _Pragma("unroll")                                                    \
    for (int jj = 0; jj < 4; ++jj) {                                     \
        const int j = (VBASE >> 2) + jj;                                 \
        const float4 z4 = *(const float4*)&zls[j * 2048 + (t << 2)];     \
        _Pragma("unroll")                                                \
        for (int c = 0; c < 4; ++c) {                                    \
            const int e = jj * 4 + c;                                    \
            const int i = j * 2048 + (t << 2) + c;                       \
            const float zc = (c == 0) ? z4.x : (c == 1) ? z4.y           \
                           : (c == 2) ? z4.z : z4.w;                     \
            const float dx = PX[e] - lx;                                 \
            const float dy = PY[e] - ly;                                 \
            const float dz = zc - lz;                                    \
            const float d = dx * dx + dy * dy + dz * dz;                 \
            const float m = fminf(MD[e], d);                             \
            MD[e] = m;                                                   \
            if (m > best) { best = m; bi = i; }                          \
        }                                                                \
    }

__global__ __launch_bounds__(FPS_T)
__attribute__((amdgpu_waves_per_eu(1)))
void fps_kernel(
    const float* __restrict__ posx, const float* __restrict__ posy,
    const float* __restrict__ posz, const float* __restrict__ pos,
    int* __restrict__ out_idx, int M)
{
    __shared__ __align__(16) float zls[32768];   // 128 KiB: z coords LDS-resident
    __shared__ unsigned long long redk[3];       // triple-buffered packed argmax

    const int t = threadIdx.x;
    const int lane = t & 63;

    vf16 px0, px1, px2, px3, py0, py1, py2, py3, md0, md1, md2, md3;
    FPS_INIT(px0, py0, md0, 0)
    FPS_INIT(px1, py1, md1, 16)
    FPS_INIT(px2, py2, md2, 32)
    FPS_INIT(px3, py3, md3, 48)

    // stage z into LDS (coalesced float4)
    for (int i = t; i < 32768 / 4; i += FPS_T)
        ((float4*)zls)[i] = ((const float4*)posz)[i];
    if (t < 3) redk[t] = 0ULL;
    if (t == 0) out_idx[0] = 0;
    __syncthreads();

    int last = 0;
    for (int s = 1; s < M; ++s) {
        // wave-uniform pick: scalar loads of its packed coords (one line)
        const int lastS = __builtin_amdgcn_readfirstlane(last);
        const float lx = pos[3 * lastS + 0];
        const float ly = pos[3 * lastS + 1];
        const float lz = pos[3 * lastS + 2];

        float best = -1.0f;
        int bi = 0x7fffffff;
        FPS_STEP(px0, py0, md0, 0)
        __builtin_amdgcn_sched_barrier(0);   // cap z-load hoisting (reg budget)
        FPS_STEP(px1, py1, md1, 16)
        __builtin_amdgcn_sched_barrier(0);
        FPS_STEP(px2, py2, md2, 32)
        __builtin_amdgcn_sched_barrier(0);
        FPS_STEP(px3, py3, md3, 48)

        // pack (value, ~index): u64 max == (max value, then lowest index).
        // mind >= 0 always, so float bits are monotonic as u32.
        unsigned long long key =
            ((unsigned long long)__float_as_uint(best) << 32) |
            (unsigned int)~bi;
#pragma unroll
        for (int off = 32; off > 0; off >>= 1) {
            const unsigned long long ok = __shfl_xor(key, off);
            key = (ok > key) ? ok : key;
        }
        const int buf = s % 3;
        if (lane == 0) atomicMax(&redk[buf], key);
        __syncthreads();
        const unsigned long long gk = redk[buf];
        const int bidx = (int)~(unsigned int)gk;
        if (t == 0) {
            out_idx[s] = bidx;
            // recycle slot for step s+3: its last readers passed barrier(s),
            // its next writers arrive after barrier(s+1) -> race-free.
            redk[(s + 2) % 3] = 0ULL;
        }
        last = bidx;
        // single barrier per step (triple-buffered reduction slot)
    }
}

// --- KNN (exact top-16 by (d, idx)) + gather-max over h + sub outputs -------
__global__ __launch_bounds__(256) void knn_kernel(
    const float* __restrict__ posx, const float* __restrict__ posy,
    const float* __restrict__ posz, const int* __restrict__ idx,
    const float* __restrict__ h, const float* __restrict__ pos,
    const int* __restrict__ batch, float* __restrict__ out,
    float* __restrict__ out_subpos, int* __restrict__ out_subbatch,
    int N, int M, int Cout)
{
    const int q = (int)((blockIdx.x * (unsigned)blockDim.x + threadIdx.x) >> 6);
    const int lane = threadIdx.x & 63;
    if (q >= M) return;

    const int qi = idx[q];
    const float qx = posx[qi], qy = posy[qi], qz = posz[qi];

    // per-lane top-16 (replace-max), wave-shared rejection threshold T
    float d16[KNN_K]; int i16[KNN_K];
#pragma unroll
    for (int k = 0; k < KNN_K; ++k) { d16[k] = __builtin_inff(); i16[k] = 0x7fffffff; }
    float lmax = __builtin_inff();
    int lslot = 0;
    float T = __builtin_inff();

    const int iters = N >> 6;
    for (int c = 0; c < iters; ++c) {
        const int p = c * 64 + lane;
        const float dx = posx[p] - qx;
        const float dy = posy[p] - qy;
        const float dz = posz[p] - qz;
        const float d = dx * dx + dy * dy + dz * dz;
        if (d < T && d < lmax) {
            d16[lslot] = d; i16[lslot] = p;
            lmax = d16[0]; lslot = 0;
#pragma unroll
            for (int k = 1; k < KNN_K; ++k)
                if (d16[k] > lmax) { lmax = d16[k]; lslot = k; }
        }
        if ((c & 31) == 31) {
            float tt = lmax;
#pragma unroll
            for (int off = 32; off > 0; off >>= 1)
                tt = fminf(tt, __shfl_xor(tt, off));
            T = tt;   // global-16th-so-far <= min over lanes of lane-16th: exact reject
        }
    }

    // merge: 16 rounds of wave extract-min with (d, idx) lexicographic order
    int nbr[KNN_K];
#pragma unroll
    for (int r = 0; r < KNN_K; ++r) {
        float lv = d16[0]; int ls = 0;
#pragma unroll
        for (int k = 1; k < KNN_K; ++k)
            if (d16[k] < lv || (d16[k] == lv && i16[k] < i16[ls])) { lv = d16[k]; ls = k; }
        float mv = lv; int mi = i16[ls];
#pragma unroll
        for (int off = 32; off > 0; off >>= 1) {
            const float ov = __shfl_xor(mv, off);
            const int   oi = __shfl_xor(mi, off);
            if (ov < mv || (ov == mv && oi < mi)) { mv = ov; mi = oi; }
        }
        if (i16[ls] == mi) d16[ls] = __builtin_inff();   // unique owner removes it
        nbr[r] = mi;
    }

    // out[q] = max over 16 neighbors of h rows (coalesced per-row loads)
    for (int c = lane; c < Cout; c += 64) {
        float a = -__builtin_inff();
#pragma unroll
        for (int r = 0; r < KNN_K; ++r)
            a = fmaxf(a, h[(size_t)nbr[r] * Cout + c]);
        out[(size_t)q * Cout + c] = a;
    }
    if (lane < 3) out_subpos[q * 3 + lane] = pos[qi * 3 + lane];
    if (lane == 3) out_subbatch[q] = batch[qi];
}

// ---------------------------------------------------------------------------
extern "C" void kernel_launch(void* const* d_in, const int* in_sizes, int n_in,
                              void* d_out, int out_size, void* d_ws, size_t ws_size,
                              hipStream_t stream)
{
    const float* x     = (const float*)d_in[0];
    const float* pos   = (const float*)d_in[1];
    const int*   batch = (const int*)d_in[2];
    const float* W     = (const float*)d_in[3];
    const float* b     = (const float*)d_in[4];

    const int N    = in_sizes[2];       // 32768 (batch has one entry per point)
    const int Cout = in_sizes[4];       // 128
    const int M    = N / 4;             // RATIO = 0.25 -> 8192

    // workspace layout (floats): posx | posy | posz | idx(int) | h[N*Cout]
    float* posx = (float*)d_ws;
    float* posy = posx + N;
    float* posz = posy + N;
    int*   idx  = (int*)(posz + N);
    float* h    = (float*)(idx + M);

    float* out          = (float*)d_out;
    float* out_subpos   = out + (size_t)M * Cout;
    int*   out_subbatch = (int*)(out_subpos + (size_t)M * 3);

    prep_kernel<<<(N + 255) / 256, 256, 0, stream>>>(pos, posx, posy, posz, N);
    mlp_kernel<<<N / MLP_ROWS, 256, 0, stream>>>(x, W, b, h, N);
    fps_kernel<<<1, FPS_T, 0, stream>>>(posx, posy, posz, pos, idx, M);
    knn_kernel<<<(M * 64) / 256, 256, 0, stream>>>(posx, posy, posz, idx, h, pos, batch,
                                                   out, out_subpos, out_subbatch, N, M, Cout);
}

// Round 4
// 35133.633 us; speedup vs baseline: 1.0021x; 1.0021x over previous
//
#include <hip/hip_runtime.h>

// ---------------------------------------------------------------------------
// TransitionDown: FPS (M=N/4) -> KNN(K=16) -> Linear(64->128)+ReLU -> max-pool
// Round 8: stop fighting the allocator — shrink the state to the budget.
// Evidence across r4-r7: a 512-thr block is hard-capped at 128 arch VGPRs
// (256/2 waves-per-SIMD residency); every attribute attempt (waves_per_eu,
// num_vgpr) left VGPR_Count at 128/64 and the 192-float state spilling.
// r6/r7 also showed sched_barrier(0) + LDS atomicMax cost 0.5us/step vs r4.
// Changes vs r4 (the 3.76us/step known-best structure):
//   - Resident registers: x + mind only (128 floats, fits budget).
//     y streams from global/L2 per step (r4's proven z-stream pattern);
//     z is LDS-resident (128 KiB, ds_read_b128).
//   - Wave argmax via DPP trees (VALU-speed) instead of 6 dependent
//     __shfl_xor (ds_bpermute, ~0.3us of serial LDS latency):
//     value tree (v_max_f32 + quad_perm/mirror/bcast) -> readlane 63,
//     then eligible-index min tree (v_min_u32). Exact (max val, lowest idx).
//   - Cross-wave: r4's double-buffered 8-slot scan (u64 keys), 1 barrier/step,
//     no atomics, no sched_barriers (let the compiler prefetch the y-stream).
// Distance math, ownership i = j*2048+4t+c, and tie-break order are
// expression-identical to the passing kernels -> bit-identical picks.
// ---------------------------------------------------------------------------

#define FPS_T   512
#define KNN_K   16
#define MLP_ROWS 32

typedef float vf16 __attribute__((ext_vector_type(16)));

// DPP helpers (compile-time ctrl constants). bound_ctrl=false + old=src:
// lanes with invalid source keep their own value (harmless for max/min).
#define DPPF(X, CTRL) __uint_as_float(__builtin_amdgcn_update_dpp(            \
    (int)__float_as_uint(X), (int)__float_as_uint(X), (CTRL), 0xf, 0xf, false))
#define DPPU(X, CTRL) ((unsigned)__builtin_amdgcn_update_dpp(                 \
    (int)(X), (int)(X), (CTRL), 0xf, 0xf, false))

// --- SoA transpose of pos for coalesced per-coordinate access ---------------
__global__ void prep_kernel(const float* __restrict__ pos, float* __restrict__ posx,
                            float* __restrict__ posy, float* __restrict__ posz, int N)
{
    const int i = blockIdx.x * blockDim.x + threadIdx.x;
    if (i < N) {
        posx[i] = pos[3 * i + 0];
        posy[i] = pos[3 * i + 1];
        posz[i] = pos[3 * i + 2];
    }
}

// --- h = relu(x @ W + b), x[N,64], W[64,128], h[N,128] ----------------------
__global__ __launch_bounds__(256) void mlp_kernel(
    const float* __restrict__ x, const float* __restrict__ W,
    const float* __restrict__ b, float* __restrict__ h, int N)
{
    __shared__ float ws[64 * 128];
    __shared__ float xs[MLP_ROWS * 65];   // +1 pad: breaks 8-way bank conflict
    const int t = threadIdx.x;
    const int r0 = blockIdx.x * MLP_ROWS;

    for (int i = t; i < 64 * 128; i += 256) ws[i] = W[i];
    for (int i = t; i < MLP_ROWS * 64; i += 256) {
        const int r = i >> 6, k = i & 63;
        xs[r * 65 + k] = x[r0 * 64 + i];
    }
    __syncthreads();

    const int tx = t & 31, ty = t >> 5;
    const int c0 = tx * 4, rr = ty * 4;    // 4 rows x 4 cols per thread
    float acc[4][4];
#pragma unroll
    for (int i = 0; i < 4; ++i)
#pragma unroll
        for (int j = 0; j < 4; ++j) acc[i][j] = 0.0f;

    for (int k = 0; k < 64; ++k) {
        const float4 w4 = *(const float4*)(&ws[k * 128 + c0]);
#pragma unroll
        for (int i = 0; i < 4; ++i) {
            const float xv = xs[(rr + i) * 65 + k];
            acc[i][0] += xv * w4.x;
            acc[i][1] += xv * w4.y;
            acc[i][2] += xv * w4.z;
            acc[i][3] += xv * w4.w;
        }
    }
    const float4 b4 = *(const float4*)(&b[c0]);
#pragma unroll
    for (int i = 0; i < 4; ++i) {
        float4 o;
        o.x = fmaxf(acc[i][0] + b4.x, 0.0f);
        o.y = fmaxf(acc[i][1] + b4.y, 0.0f);
        o.z = fmaxf(acc[i][2] + b4.z, 0.0f);
        o.w = fmaxf(acc[i][3] + b4.w, 0.0f);
        *(float4*)(&h[(size_t)(r0 + rr + i) * 128 + c0]) = o;
    }
}

// --- Farthest point sampling: exact sequential semantics --------------------
// idx = [0, pick_0, ..., pick_{M-2}]; pick = argmax of updated mind,
// ties -> lowest index (matches jnp.argmax).
// Ownership: thread t, slot k in [0,64): i = (k>>2)*2048 + 4t + (k&3).
// Ascending i per thread => strict '>' keeps lowest index on tie within a
// thread; the DPP eligible-min tree and u64 slot keys handle cross-lane/wave.
#define FPS_INIT(PX, MD, VBASE)                                           \
    _Pragma("unroll")                                                     \
    for (int jj = 0; jj < 4; ++jj) {                                      \
        const int j = (VBASE >> 2) + jj;                                  \
        const float4 x4 = *(const float4*)&posx[j * 2048 + (t << 2)];     \
        PX[jj * 4 + 0] = x4.x; PX[jj * 4 + 1] = x4.y;                     \
        PX[jj * 4 + 2] = x4.z; PX[jj * 4 + 3] = x4.w;                     \
        _Pragma("unroll")                                                 \
        for (int c = 0; c < 4; ++c) MD[jj * 4 + c] = __builtin_inff();    \
    }

#define FPS_STEP(PX, MD, VBASE)                                          \
    _Pragma("unroll")                                                    \
    for (int jj = 0; jj < 4; ++jj) {                                     \
        const int j = (VBASE >> 2) + jj;                                 \
        const float4 y4 = *(const float4*)&posy[j * 2048 + (t << 2)];    \
        const float4 z4 = *(const float4*)&zls[j * 2048 + (t << 2)];     \
        _Pragma("unroll")                                                \
        for (int c = 0; c < 4; ++c) {                                    \
            const int e = jj * 4 + c;                                    \
            const int i = j * 2048 + (t << 2) + c;                       \
            const float yc = (c == 0) ? y4.x : (c == 1) ? y4.y           \
                           : (c == 2) ? y4.z : y4.w;                     \
            const float zc = (c == 0) ? z4.x : (c == 1) ? z4.y           \
                           : (c == 2) ? z4.z : z4.w;                     \
            const float dx = PX[e] - lx;                                 \
            const float dy = yc - ly;                                    \
            const float dz = zc - lz;                                    \
            const float d = dx * dx + dy * dy + dz * dz;                 \
            const float m = fminf(MD[e], d);                             \
            MD[e] = m;                                                   \
            if (m > best) { best = m; bi = i; }                          \
        }                                                                \
    }

__global__ __launch_bounds__(FPS_T) void fps_kernel(
    const float* __restrict__ posx, const float* __restrict__ posy,
    const float* __restrict__ posz, const float* __restrict__ pos,
    int* __restrict__ out_idx, int M)
{
    __shared__ __align__(16) float zls[32768];       // 128 KiB: z LDS-resident
    __shared__ unsigned long long redk[2][FPS_T / 64];  // dbuf'd per-wave keys

    const int t = threadIdx.x;
    const int wid = t >> 6;
    const int lane = t & 63;

    vf16 px0, px1, px2, px3, md0, md1, md2, md3;     // 128 floats resident
    FPS_INIT(px0, md0, 0)
    FPS_INIT(px1, md1, 16)
    FPS_INIT(px2, md2, 32)
    FPS_INIT(px3, md3, 48)

    // stage z into LDS (coalesced float4)
    for (int i = t; i < 32768 / 4; i += FPS_T)
        ((float4*)zls)[i] = ((const float4*)posz)[i];
    if (t == 0) out_idx[0] = 0;
    __syncthreads();

    int last = 0;
    for (int s = 1; s < M; ++s) {
        // wave-uniform pick coords: scalar loads (x,y global L2; z LDS)
        const int lastS = __builtin_amdgcn_readfirstlane(last);
        const float lx = posx[lastS];
        const float ly = posy[lastS];
        const float lz = zls[lastS];

        float best = -1.0f;
        int bi = 0x7fffffff;
        FPS_STEP(px0, md0, 0)
        FPS_STEP(px1, md1, 16)
        FPS_STEP(px2, md2, 32)
        FPS_STEP(px3, md3, 48)

        // ---- wave argmax, VALU-speed (DPP), exact (max val, lowest idx) ----
        // value tree -> lane 63 holds max over 64 lanes
        float v = best;
        v = fmaxf(v, DPPF(v, 0xB1));   // quad_perm(1,0,3,2)  = xor 1
        v = fmaxf(v, DPPF(v, 0x4E));   // quad_perm(2,3,0,1)  = xor 2
        v = fmaxf(v, DPPF(v, 0x141));  // row_half_mirror     -> max over 8
        v = fmaxf(v, DPPF(v, 0x140));  // row_mirror          -> max over 16
        v = fmaxf(v, DPPF(v, 0x142));  // row_bcast15         -> max over 32
        v = fmaxf(v, DPPF(v, 0x143));  // row_bcast31         -> max over 64
        const unsigned maxbits =
            (unsigned)__builtin_amdgcn_readlane((int)__float_as_uint(v), 63);
        // eligible-index min tree (lanes holding the max value)
        unsigned ei = (__float_as_uint(best) == maxbits) ? (unsigned)bi
                                                         : 0xffffffffu;
        ei = min(ei, DPPU(ei, 0xB1));
        ei = min(ei, DPPU(ei, 0x4E));
        ei = min(ei, DPPU(ei, 0x141));
        ei = min(ei, DPPU(ei, 0x140));
        ei = min(ei, DPPU(ei, 0x142));
        ei = min(ei, DPPU(ei, 0x143));
        const unsigned biw =
            (unsigned)__builtin_amdgcn_readlane((int)ei, 63);

        // ---- cross-wave: 8-slot scan of packed u64 keys (no atomics) -------
        // key = (val_bits<<32) | ~idx : u64 max == (max val, then lowest idx)
        const int buf = s & 1;
        if (lane == 0)
            redk[buf][wid] =
                ((unsigned long long)maxbits << 32) | (unsigned int)~biw;
        __syncthreads();
        unsigned long long kk = redk[buf][0];
#pragma unroll
        for (int w = 1; w < FPS_T / 64; ++w) {
            const unsigned long long o = redk[buf][w];
            kk = (o > kk) ? o : kk;
        }
        const int bidx = (int)~(unsigned int)kk;
        if (t == 0) out_idx[s] = bidx;
        last = bidx;
        // single barrier per step: next step writes the other redk buffer
    }
}

// --- KNN (exact top-16 by (d, idx)) + gather-max over h + sub outputs -------
__global__ __launch_bounds__(256) void knn_kernel(
    const float* __restrict__ posx, const float* __restrict__ posy,
    const float* __restrict__ posz, const int* __restrict__ idx,
    const float* __restrict__ h, const float* __restrict__ pos,
    const int* __restrict__ batch, float* __restrict__ out,
    float* __restrict__ out_subpos, int* __restrict__ out_subbatch,
    int N, int M, int Cout)
{
    const int q = (int)((blockIdx.x * (unsigned)blockDim.x + threadIdx.x) >> 6);
    const int lane = threadIdx.x & 63;
    if (q >= M) return;

    const int qi = idx[q];
    const float qx = posx[qi], qy = posy[qi], qz = posz[qi];

    // per-lane top-16 (replace-max), wave-shared rejection threshold T
    float d16[KNN_K]; int i16[KNN_K];
#pragma unroll
    for (int k = 0; k < KNN_K; ++k) { d16[k] = __builtin_inff(); i16[k] = 0x7fffffff; }
    float lmax = __builtin_inff();
    int lslot = 0;
    float T = __builtin_inff();

    const int iters = N >> 6;
    for (int c = 0; c < iters; ++c) {
        const int p = c * 64 + lane;
        const float dx = posx[p] - qx;
        const float dy = posy[p] - qy;
        const float dz = posz[p] - qz;
        const float d = dx * dx + dy * dy + dz * dz;
        if (d < T && d < lmax) {
            d16[lslot] = d; i16[lslot] = p;
            lmax = d16[0]; lslot = 0;
#pragma unroll
            for (int k = 1; k < KNN_K; ++k)
                if (d16[k] > lmax) { lmax = d16[k]; lslot = k; }
        }
        if ((c & 31) == 31) {
            float tt = lmax;
#pragma unroll
            for (int off = 32; off > 0; off >>= 1)
                tt = fminf(tt, __shfl_xor(tt, off));
            T = tt;   // global-16th-so-far <= min over lanes of lane-16th: exact reject
        }
    }

    // merge: 16 rounds of wave extract-min with (d, idx) lexicographic order
    int nbr[KNN_K];
#pragma unroll
    for (int r = 0; r < KNN_K; ++r) {
        float lv = d16[0]; int ls = 0;
#pragma unroll
        for (int k = 1; k < KNN_K; ++k)
            if (d16[k] < lv || (d16[k] == lv && i16[k] < i16[ls])) { lv = d16[k]; ls = k; }
        float mv = lv; int mi = i16[ls];
#pragma unroll
        for (int off = 32; off > 0; off >>= 1) {
            const float ov = __shfl_xor(mv, off);
            const int   oi = __shfl_xor(mi, off);
            if (ov < mv || (ov == mv && oi < mi)) { mv = ov; mi = oi; }
        }
        if (i16[ls] == mi) d16[ls] = __builtin_inff();   // unique owner removes it
        nbr[r] = mi;
    }

    // out[q] = max over 16 neighbors of h rows (coalesced per-row loads)
    for (int c = lane; c < Cout; c += 64) {
        float a = -__builtin_inff();
#pragma unroll
        for (int r = 0; r < KNN_K; ++r)
            a = fmaxf(a, h[(size_t)nbr[r] * Cout + c]);
        out[(size_t)q * Cout + c] = a;
    }
    if (lane < 3) out_subpos[q * 3 + lane] = pos[qi * 3 + lane];
    if (lane == 3) out_subbatch[q] = batch[qi];
}

// ---------------------------------------------------------------------------
extern "C" void kernel_launch(void* const* d_in, const int* in_sizes, int n_in,
                              void* d_out, int out_size, void* d_ws, size_t ws_size,
                              hipStream_t stream)
{
    const float* x     = (const float*)d_in[0];
    const float* pos   = (const float*)d_in[1];
    const int*   batch = (const int*)d_in[2];
    const float* W     = (const float*)d_in[3];
    const float* b     = (const float*)d_in[4];

    const int N    = in_sizes[2];       // 32768 (batch has one entry per point)
    const int Cout = in_sizes[4];       // 128
    const int M    = N / 4;             // RATIO = 0.25 -> 8192

    // workspace layout (floats): posx | posy | posz | idx(int) | h[N*Cout]
    float* posx = (float*)d_ws;
    float* posy = posx + N;
    float* posz = posy + N;
    int*   idx  = (int*)(posz + N);
    float* h    = (float*)(idx + M);

    float* out          = (float*)d_out;
    float* out_subpos   = out + (size_t)M * Cout;
    int*   out_subbatch = (int*)(out_subpos + (size_t)M * 3);

    prep_kernel<<<(N + 255) / 256, 256, 0, stream>>>(pos, posx, posy, posz, N);
    mlp_kernel<<<N / MLP_ROWS, 256, 0, stream>>>(x, W, b, h, N);
    fps_kernel<<<1, FPS_T, 0, stream>>>(posx, posy, posz, pos, idx, M);
    knn_kernel<<<(M * 64) / 256, 256, 0, stream>>>(posx, posy, posz, idx, h, pos, batch,
                                                   out, out_subpos, out_subbatch, N, M, Cout);
}

// Round 5
// 22382.320 us; speedup vs baseline: 1.5730x; 1.5697x over previous
//
#include <hip/hip_runtime.h>

// ---------------------------------------------------------------------------
// TransitionDown: FPS (M=N/4) -> KNN(K=16) -> Linear(64->128)+ReLU -> max-pool
// Round 9: algorithmic FPS. r4-r8 proved the brute-force sweep structure is
// the floor (~4us/step regardless of register layout): 32K-point sweep
// streams 128KB/step through one CU's L2/LDS port + serial reduce chain.
// Replace with exact chunk-pruned FPS (QuickFPS-style, bit-exact):
//   - mind_i = min over picks of d(i,pick): min is order-independent and
//     only decreases => lazy update is EXACT.
//   - Morton counting sort (permutation only; orig idx kept) -> 512 chunks
//     of 64 pts with tight bboxes.
//   - skip chunk iff d_lb(pick,bbox)*0.99999 >= chunkmax  (slack strictly
//     covers fp rounding incl. fma contraction => a skip can NEVER change
//     any mind value => picks bit-identical to brute force).
//   - per-step argmax = reduce over 512 stored chunk keys
//     (u64 (val<<32)|~orig: max == (max val, then lowest orig idx) — the
//     tie-exact key validated in r6-r8).
//   - mind[32K] in LDS (128KB); bbox/meta in LDS; coords L2-resident.
// Sort buffers alias the h region; mlp launched AFTER fps (same stream).
// knn / mlp / prep unchanged.
// ---------------------------------------------------------------------------

#define FPS_T   512
#define NC      512          // chunks = FPS_T (one chunk per thread in phase 1)
#define KNN_K   16
#define MLP_ROWS 32

// --- SoA transpose of pos for coalesced per-coordinate access ---------------
__global__ void prep_kernel(const float* __restrict__ pos, float* __restrict__ posx,
                            float* __restrict__ posy, float* __restrict__ posz, int N)
{
    const int i = blockIdx.x * blockDim.x + threadIdx.x;
    if (i < N) {
        posx[i] = pos[3 * i + 0];
        posy[i] = pos[3 * i + 1];
        posz[i] = pos[3 * i + 2];
    }
}

// --- Morton-bucket counting sort (spatial permutation; exact semantics kept
//     by carrying orig index). Cell = 4 bits/dim quantized, bits interleaved.
__device__ __forceinline__ unsigned spread4(unsigned x)
{
    return (x & 1u) | ((x & 2u) << 2) | ((x & 4u) << 4) | ((x & 8u) << 6);
}
__device__ __forceinline__ unsigned mcode(float x, float y, float z)
{
    // data ~ N(0,1): [-6,6] covers; clamp handles outliers (heuristic only —
    // any code is correct, it just shapes chunk locality).
    int qx = (int)((x + 6.0f) * (16.0f / 12.0f));
    int qy = (int)((y + 6.0f) * (16.0f / 12.0f));
    int qz = (int)((z + 6.0f) * (16.0f / 12.0f));
    qx = qx < 0 ? 0 : (qx > 15 ? 15 : qx);
    qy = qy < 0 ? 0 : (qy > 15 ? 15 : qy);
    qz = qz < 0 ? 0 : (qz > 15 ? 15 : qz);
    return spread4((unsigned)qx) | (spread4((unsigned)qy) << 1)
         | (spread4((unsigned)qz) << 2);
}

__global__ __launch_bounds__(1024) void sort_kernel(
    const float* __restrict__ posx, const float* __restrict__ posy,
    const float* __restrict__ posz, float* __restrict__ xs,
    float* __restrict__ ys, float* __restrict__ zs,
    unsigned* __restrict__ orig, int N)
{
    __shared__ unsigned cnt[4096];
    __shared__ unsigned base[4096];
    const int t = threadIdx.x;

    for (int i = t; i < 4096; i += 1024) cnt[i] = 0;
    __syncthreads();
    for (int i = t; i < N; i += 1024)
        atomicAdd(&cnt[mcode(posx[i], posy[i], posz[i])], 1u);
    __syncthreads();
    if (t == 0) {                       // serial scan: once, ~4096 LDS ops
        unsigned run = 0;
        for (int c = 0; c < 4096; ++c) { base[c] = run; run += cnt[c]; }
    }
    __syncthreads();
    for (int i = t; i < 4096; i += 1024) cnt[i] = 0;
    __syncthreads();
    for (int i = t; i < N; i += 1024) {
        const float px = posx[i], py = posy[i], pz = posz[i];
        const unsigned m = mcode(px, py, pz);
        const unsigned d = base[m] + atomicAdd(&cnt[m], 1u);
        xs[d] = px; ys[d] = py; zs[d] = pz; orig[d] = (unsigned)i;
    }
}

// --- per-chunk bbox (exact fmin/fmax of member coords) ----------------------
__global__ __launch_bounds__(64) void bbox_kernel(
    const float* __restrict__ xs, const float* __restrict__ ys,
    const float* __restrict__ zs, float* __restrict__ bboxG)
{
    const int c = blockIdx.x, l = threadIdx.x;
    const int i = c * 64 + l;
    float xmn = xs[i], xmx = xmn;
    float ymn = ys[i], ymx = ymn;
    float zmn = zs[i], zmx = zmn;
#pragma unroll
    for (int off = 32; off > 0; off >>= 1) {
        xmn = fminf(xmn, __shfl_xor(xmn, off));
        xmx = fmaxf(xmx, __shfl_xor(xmx, off));
        ymn = fminf(ymn, __shfl_xor(ymn, off));
        ymx = fmaxf(ymx, __shfl_xor(ymx, off));
        zmn = fminf(zmn, __shfl_xor(zmn, off));
        zmx = fmaxf(zmx, __shfl_xor(zmx, off));
    }
    if (l == 0) {
        float* o = &bboxG[c * 6];
        o[0] = xmn; o[1] = xmx; o[2] = ymn; o[3] = ymx; o[4] = zmn; o[5] = zmx;
    }
}

// --- h = relu(x @ W + b), x[N,64], W[64,128], h[N,128] ----------------------
__global__ __launch_bounds__(256) void mlp_kernel(
    const float* __restrict__ x, const float* __restrict__ W,
    const float* __restrict__ b, float* __restrict__ h, int N)
{
    __shared__ float ws[64 * 128];
    __shared__ float xs[MLP_ROWS * 65];   // +1 pad: breaks 8-way bank conflict
    const int t = threadIdx.x;
    const int r0 = blockIdx.x * MLP_ROWS;

    for (int i = t; i < 64 * 128; i += 256) ws[i] = W[i];
    for (int i = t; i < MLP_ROWS * 64; i += 256) {
        const int r = i >> 6, k = i & 63;
        xs[r * 65 + k] = x[r0 * 64 + i];
    }
    __syncthreads();

    const int tx = t & 31, ty = t >> 5;
    const int c0 = tx * 4, rr = ty * 4;    // 4 rows x 4 cols per thread
    float acc[4][4];
#pragma unroll
    for (int i = 0; i < 4; ++i)
#pragma unroll
        for (int j = 0; j < 4; ++j) acc[i][j] = 0.0f;

    for (int k = 0; k < 64; ++k) {
        const float4 w4 = *(const float4*)(&ws[k * 128 + c0]);
#pragma unroll
        for (int i = 0; i < 4; ++i) {
            const float xv = xs[(rr + i) * 65 + k];
            acc[i][0] += xv * w4.x;
            acc[i][1] += xv * w4.y;
            acc[i][2] += xv * w4.z;
            acc[i][3] += xv * w4.w;
        }
    }
    const float4 b4 = *(const float4*)(&b[c0]);
#pragma unroll
    for (int i = 0; i < 4; ++i) {
        float4 o;
        o.x = fmaxf(acc[i][0] + b4.x, 0.0f);
        o.y = fmaxf(acc[i][1] + b4.y, 0.0f);
        o.z = fmaxf(acc[i][2] + b4.z, 0.0f);
        o.w = fmaxf(acc[i][3] + b4.w, 0.0f);
        *(float4*)(&h[(size_t)(r0 + rr + i) * 128 + c0]) = o;
    }
}

// --- Farthest point sampling: exact, chunk-pruned ---------------------------
// idx = [0, pick_1, ..., pick_{M-1}]; pick = argmax over exact mind,
// ties -> lowest ORIGINAL index (u64 key (val<<32)|~orig, max-reduce).
// Skip rule: d_lb(pick, chunk bbox)*0.99999 >= chunkmax  =>  for every i in
// chunk, d(i,pick) >= d_lb_true > d_lb_scaled >= chunkmax >= mind_i, so
// fminf leaves mind_i unchanged — skip is bit-exact.
__global__ __launch_bounds__(FPS_T) void fps_kernel(
    const float* __restrict__ xs, const float* __restrict__ ys,
    const float* __restrict__ zs, const unsigned* __restrict__ orig,
    const float* __restrict__ bboxG, int* __restrict__ out_idx, int M, int N)
{
    __shared__ float mind[32768];                 // 128 KB, sorted order
    __shared__ float bb[6][NC];                   // bbox SoA
    __shared__ float cmax[NC];                    // exact max(mind) per chunk
    __shared__ unsigned long long ckey[NC];       // exact (max, ~orig) per chunk
    __shared__ unsigned csid[NC];                 // sorted idx of chunk winner
    __shared__ unsigned alist[NC];
    __shared__ unsigned acnt[2];
    __shared__ unsigned long long wslot[2][8];
    __shared__ unsigned wsid[2][8];
    __shared__ unsigned spick0;

    const int t = threadIdx.x;
    const int wid = t >> 6;
    const int lane = t & 63;

    for (int i = t; i < 32768; i += FPS_T) mind[i] = __builtin_inff();
    for (int c = t; c < NC; c += FPS_T) {
        cmax[c] = __builtin_inff();
        ckey[c] = 0ULL; csid[c] = 0;
        const float* bsrc = &bboxG[c * 6];
        bb[0][c] = bsrc[0]; bb[1][c] = bsrc[1]; bb[2][c] = bsrc[2];
        bb[3][c] = bsrc[3]; bb[4][c] = bsrc[4]; bb[5][c] = bsrc[5];
    }
    if (t == 0) { acnt[0] = 0; acnt[1] = 0; out_idx[0] = 0; }
    for (int i = t; i < N; i += FPS_T)
        if (orig[i] == 0u) spick0 = (unsigned)i;   // unique writer
    __syncthreads();

    unsigned sp = spick0;
    float lx = xs[sp], ly = ys[sp], lz = zs[sp];

    for (int s = 1; s < M; ++s) {
        const int buf = s & 1;

        // ---- phase 1: bound test, chunk c == t ----------------------------
        {
            const float gx = fmaxf(fmaxf(bb[0][t] - lx, lx - bb[1][t]), 0.0f);
            const float gy = fmaxf(fmaxf(bb[2][t] - ly, ly - bb[3][t]), 0.0f);
            const float gz = fmaxf(fmaxf(bb[4][t] - lz, lz - bb[5][t]), 0.0f);
            const float dlb = (gx * gx + gy * gy + gz * gz) * 0.99999f;
            if (dlb < cmax[t])
                alist[atomicAdd(&acnt[buf], 1u)] = (unsigned)t;
        }
        __syncthreads();                                   // A
        const int na = (int)acnt[buf];

        // ---- phase 2: exact update of active chunks (wave per chunk) ------
        for (int i = wid; i < na; i += FPS_T / 64) {
            const int cc = (int)alist[i];
            const int sidx = cc * 64 + lane;
            const float dx = xs[sidx] - lx;
            const float dy = ys[sidx] - ly;
            const float dz = zs[sidx] - lz;
            const float d = dx * dx + dy * dy + dz * dz;
            const float m = fminf(mind[sidx], d);
            mind[sidx] = m;
            unsigned long long k =
                ((unsigned long long)__float_as_uint(m) << 32)
                | (unsigned)~orig[sidx];
            unsigned si = (unsigned)sidx;
#pragma unroll
            for (int off = 32; off > 0; off >>= 1) {
                const unsigned long long ok = __shfl_xor(k, off);
                const unsigned osi = __shfl_xor(si, off);
                if (ok > k) { k = ok; si = osi; }
            }
            if (lane == 0) {
                ckey[cc] = k; csid[cc] = si;
                cmax[cc] = __uint_as_float((unsigned)(k >> 32));
            }
        }
        __syncthreads();                                   // B

        // ---- phase 3: global argmax over 512 exact chunk keys -------------
        unsigned long long k = ckey[t];
        unsigned si = csid[t];
#pragma unroll
        for (int off = 32; off > 0; off >>= 1) {
            const unsigned long long ok = __shfl_xor(k, off);
            const unsigned osi = __shfl_xor(si, off);
            if (ok > k) { k = ok; si = osi; }
        }
        if (lane == 0) { wslot[buf][wid] = k; wsid[buf][wid] = si; }
        if (t == 0) acnt[buf] = 0;                         // reset for s+2
        __syncthreads();                                   // C
        unsigned long long wk = wslot[buf][0];
        unsigned wsi = wsid[buf][0];
#pragma unroll
        for (int w = 1; w < FPS_T / 64; ++w) {
            const unsigned long long o = wslot[buf][w];
            if (o > wk) { wk = o; wsi = wsid[buf][w]; }
        }
        if (t == 0) out_idx[s] = (int)~(unsigned)wk;
        sp = wsi;
        lx = xs[sp]; ly = ys[sp]; lz = zs[sp];
        // no 4th barrier: wslot[buf] next written at s+2 (after A,B,C of s+1)
    }
}

// --- KNN (exact top-16 by (d, idx)) + gather-max over h + sub outputs -------
__global__ __launch_bounds__(256) void knn_kernel(
    const float* __restrict__ posx, const float* __restrict__ posy,
    const float* __restrict__ posz, const int* __restrict__ idx,
    const float* __restrict__ h, const float* __restrict__ pos,
    const int* __restrict__ batch, float* __restrict__ out,
    float* __restrict__ out_subpos, int* __restrict__ out_subbatch,
    int N, int M, int Cout)
{
    const int q = (int)((blockIdx.x * (unsigned)blockDim.x + threadIdx.x) >> 6);
    const int lane = threadIdx.x & 63;
    if (q >= M) return;

    const int qi = idx[q];
    const float qx = posx[qi], qy = posy[qi], qz = posz[qi];

    // per-lane top-16 (replace-max), wave-shared rejection threshold T
    float d16[KNN_K]; int i16[KNN_K];
#pragma unroll
    for (int k = 0; k < KNN_K; ++k) { d16[k] = __builtin_inff(); i16[k] = 0x7fffffff; }
    float lmax = __builtin_inff();
    int lslot = 0;
    float T = __builtin_inff();

    const int iters = N >> 6;
    for (int c = 0; c < iters; ++c) {
        const int p = c * 64 + lane;
        const float dx = posx[p] - qx;
        const float dy = posy[p] - qy;
        const float dz = posz[p] - qz;
        const float d = dx * dx + dy * dy + dz * dz;
        if (d < T && d < lmax) {
            d16[lslot] = d; i16[lslot] = p;
            lmax = d16[0]; lslot = 0;
#pragma unroll
            for (int k = 1; k < KNN_K; ++k)
                if (d16[k] > lmax) { lmax = d16[k]; lslot = k; }
        }
        if ((c & 31) == 31) {
            float tt = lmax;
#pragma unroll
            for (int off = 32; off > 0; off >>= 1)
                tt = fminf(tt, __shfl_xor(tt, off));
            T = tt;   // global-16th-so-far <= min over lanes of lane-16th: exact reject
        }
    }

    // merge: 16 rounds of wave extract-min with (d, idx) lexicographic order
    int nbr[KNN_K];
#pragma unroll
    for (int r = 0; r < KNN_K; ++r) {
        float lv = d16[0]; int ls = 0;
#pragma unroll
        for (int k = 1; k < KNN_K; ++k)
            if (d16[k] < lv || (d16[k] == lv && i16[k] < i16[ls])) { lv = d16[k]; ls = k; }
        float mv = lv; int mi = i16[ls];
#pragma unroll
        for (int off = 32; off > 0; off >>= 1) {
            const float ov = __shfl_xor(mv, off);
            const int   oi = __shfl_xor(mi, off);
            if (ov < mv || (ov == mv && oi < mi)) { mv = ov; mi = oi; }
        }
        if (i16[ls] == mi) d16[ls] = __builtin_inff();   // unique owner removes it
        nbr[r] = mi;
    }

    // out[q] = max over 16 neighbors of h rows (coalesced per-row loads)
    for (int c = lane; c < Cout; c += 64) {
        float a = -__builtin_inff();
#pragma unroll
        for (int r = 0; r < KNN_K; ++r)
            a = fmaxf(a, h[(size_t)nbr[r] * Cout + c]);
        out[(size_t)q * Cout + c] = a;
    }
    if (lane < 3) out_subpos[q * 3 + lane] = pos[qi * 3 + lane];
    if (lane == 3) out_subbatch[q] = batch[qi];
}

// ---------------------------------------------------------------------------
extern "C" void kernel_launch(void* const* d_in, const int* in_sizes, int n_in,
                              void* d_out, int out_size, void* d_ws, size_t ws_size,
                              hipStream_t stream)
{
    const float* x     = (const float*)d_in[0];
    const float* pos   = (const float*)d_in[1];
    const int*   batch = (const int*)d_in[2];
    const float* W     = (const float*)d_in[3];
    const float* b     = (const float*)d_in[4];

    const int N    = in_sizes[2];       // 32768 (batch has one entry per point)
    const int Cout = in_sizes[4];       // 128
    const int M    = N / 4;             // RATIO = 0.25 -> 8192

    // workspace layout (floats): posx | posy | posz | idx(int) | h[N*Cout]
    float* posx = (float*)d_ws;
    float* posy = posx + N;
    float* posz = posy + N;
    int*   idx  = (int*)(posz + N);
    float* h    = (float*)(idx + M);

    // sort/bbox scratch ALIASES the h region (fps finishes before mlp writes
    // h; single stream serializes): xs|ys|zs|orig|bboxG = 4N + 3072 floats.
    float*    xs    = h;
    float*    ys    = xs + N;
    float*    zs    = ys + N;
    unsigned* orig  = (unsigned*)(zs + N);
    float*    bboxG = (float*)(orig + N);

    float* out          = (float*)d_out;
    float* out_subpos   = out + (size_t)M * Cout;
    int*   out_subbatch = (int*)(out_subpos + (size_t)M * 3);

    prep_kernel<<<(N + 255) / 256, 256, 0, stream>>>(pos, posx, posy, posz, N);
    sort_kernel<<<1, 1024, 0, stream>>>(posx, posy, posz, xs, ys, zs, orig, N);
    bbox_kernel<<<NC, 64, 0, stream>>>(xs, ys, zs, bboxG);
    fps_kernel<<<1, FPS_T, 0, stream>>>(xs, ys, zs, orig, bboxG, idx, M, N);
    mlp_kernel<<<N / MLP_ROWS, 256, 0, stream>>>(x, W, b, h, N);
    knn_kernel<<<(M * 64) / 256, 256, 0, stream>>>(posx, posy, posz, idx, h, pos, batch,
                                                   out, out_subpos, out_subbatch, N, M, Cout);
}